// Round 2
// baseline (182.104 us; speedup 1.0000x reference)
//
#include <hip/hip_runtime.h>

// Problem constants: B=64, Cin=512, Cout=512, H=W=28 (HW=784), K=8 experts.
#define NB 64
#define CIN 512
#define COUT 512
#define HW 784
#define KEXP 8

typedef __attribute__((ext_vector_type(8))) short bf16x8;   // 8 bf16 = 4 VGPR (MFMA A/B frag)
typedef __attribute__((ext_vector_type(4))) float f32x4;    // MFMA C/D frag

typedef const __attribute__((address_space(1))) unsigned int GU32;
typedef __attribute__((address_space(3))) unsigned int LU32;

__device__ __forceinline__ unsigned f2bf1(float f) {
  unsigned u = __builtin_bit_cast(unsigned, f);
  return (u + 0x7FFFu + ((u >> 16) & 1u)) >> 16;   // RNE fp32->bf16
}
__device__ __forceinline__ unsigned f2bf2(float lo, float hi) {
  return f2bf1(lo) | (f2bf1(hi) << 16);
}

// ---------------- Kernel 1: pooled[b][c] = mean(x[b][c][:,:]) --------------
// one wave per (b,c) row; 32768 rows; 8192 blocks x 4 waves.
__global__ __launch_bounds__(256) void pool_kernel(const float* __restrict__ x,
                                                   float* __restrict__ pooled) {
  int w = threadIdx.x >> 6, lane = threadIdx.x & 63;
  int row = blockIdx.x * 4 + w;                     // < 32768 (grid 8192)
  const float4* xr = (const float4*)(x + (size_t)row * HW);
  float s = 0.f;
  for (int i = lane; i < 196; i += 64) {            // 196 float4 = 784 floats
    float4 v = xr[i];
    s += (v.x + v.y) + (v.z + v.w);
  }
  #pragma unroll
  for (int off = 32; off; off >>= 1) s += __shfl_down(s, off);
  if (lane == 0) pooled[row] = s * (1.0f / 784.0f);
}

// ---------------- Kernel 2: gate + sparsemax ------------------------------
// one block, 512 threads: thread t computes logit[b=t>>3][k=t&7]; then 64
// threads do the K=8 sparsemax serially (tiny).
__global__ __launch_bounds__(512) void gate_kernel(const float* __restrict__ pooled,
                                                   const float* __restrict__ gw,
                                                   const float* __restrict__ gb,
                                                   float* __restrict__ g) {
  __shared__ float lz[NB][KEXP];
  int t = threadIdx.x;
  int b = t >> 3, k = t & 7;
  const float4* pr = (const float4*)(pooled + b * CIN);
  const float4* wr = (const float4*)(gw + k * CIN);
  float s = 0.f;
  #pragma unroll 4
  for (int c4 = 0; c4 < 128; ++c4) {
    float4 p = pr[c4], q = wr[c4];
    s += p.x * q.x + p.y * q.y + p.z * q.z + p.w * q.w;
  }
  lz[b][k] = s + gb[k];
  __syncthreads();
  if (t < NB) {
    float z[8], zs[8];
    #pragma unroll
    for (int j = 0; j < 8; ++j) { z[j] = lz[t][j]; zs[j] = z[j]; }
    // insertion sort descending
    #pragma unroll
    for (int a = 1; a < 8; ++a) {
      float v = zs[a]; int j = a;
      while (j > 0 && zs[j - 1] < v) { zs[j] = zs[j - 1]; --j; }
      zs[j] = v;
    }
    float cums[8]; float csum = 0.f;
    #pragma unroll
    for (int j = 0; j < 8; ++j) { csum += zs[j]; cums[j] = csum; }
    int kz = 0;
    #pragma unroll
    for (int j = 0; j < 8; ++j)
      if (1.0f + (float)(j + 1) * zs[j] > cums[j]) kz = j + 1;
    float tau = (cums[kz - 1] - 1.0f) / (float)kz;
    #pragma unroll
    for (int j = 0; j < 8; ++j) g[t * 8 + j] = fmaxf(z[j] - tau, 0.0f);
  }
}

// ---------------- Kernel 3: w_eff builder (bf16, GEMM-tiled layout) -------
// Layout (16B units): unit(b,o,i) = b*32768 + ((o>>7)*16 + (i>>5))*512
//                                   + ((i>>3)&3)*128 + (o&127)
// i.e. per (b, mblk, kk) an 8KB slab laid out [kgrp(4)][row(128)][8 bf16],
// exactly what gemm's global_load_lds wants, linearly.
// Block: o-tile 16 x i-tile 128; thread holds E[k][o][i..i+7] in regs (64 f32)
// and loops all 64 batches -> E read ~once total.
__global__ __launch_bounds__(256) void weff_kernel(const float* __restrict__ E,
                                                   const float* __restrict__ g,
                                                   uint4* __restrict__ wt) {
  __shared__ float gs[NB * KEXP];
  int t = threadIdx.x;
  ((float2*)gs)[t] = ((const float2*)g)[t];         // 256 * 2 = 512 floats
  int o = blockIdx.x * 16 + (t & 15);
  int i = blockIdx.y * 128 + (t >> 4) * 8;
  float e[8][8];
  #pragma unroll
  for (int k = 0; k < 8; ++k) {
    const float4* p = (const float4*)(E + (size_t)k * (COUT * CIN) + (size_t)o * CIN + i);
    float4 a = p[0], c = p[1];
    e[k][0] = a.x; e[k][1] = a.y; e[k][2] = a.z; e[k][3] = a.w;
    e[k][4] = c.x; e[k][5] = c.y; e[k][6] = c.z; e[k][7] = c.w;
  }
  __syncthreads();
  int base = ((o >> 7) * 16 + (i >> 5)) * 512 + ((i >> 3) & 3) * 128 + (o & 127);
  for (int b = 0; b < NB; ++b) {
    float acc[8] = {0, 0, 0, 0, 0, 0, 0, 0};
    #pragma unroll
    for (int k = 0; k < 8; ++k) {
      float gv = gs[b * 8 + k];
      #pragma unroll
      for (int j = 0; j < 8; ++j) acc[j] += gv * e[k][j];
    }
    uint4 pk;
    pk.x = f2bf2(acc[0], acc[1]); pk.y = f2bf2(acc[2], acc[3]);
    pk.z = f2bf2(acc[4], acc[5]); pk.w = f2bf2(acc[6], acc[7]);
    wt[(size_t)base + (size_t)b * 32768] = pk;
  }
}

// ---------------- Kernel 4: batched GEMM ----------------------------------
// out[b][128 o][112 hw] tile = A(w_eff bf16, LDS via global_load_lds x16B)
//                              x B(x fp32 -> bf16, reg-staged, swizzled LDS)
// 4 waves split M (32 rows each); per wave 2x7 mfma_16x16x32 tiles; BK=32.
__global__ __launch_bounds__(256) void gemm_kernel(const uint4* __restrict__ weff,
                                                   const float* __restrict__ x,
                                                   float* __restrict__ out) {
  __shared__ uint4 ldsA[512];   // [kgrp4][row128] 16B units
  __shared__ uint4 ldsB[448];   // [kgrp4][col112] 16B units, unit-XOR swizzled
  int t = threadIdx.x;
  int lane = t & 63, w = t >> 6;
  int l15 = lane & 15, l4 = lane >> 4;
  int nb = blockIdx.x, mb = blockIdx.y, b = blockIdx.z;

  const float* xb = x + (size_t)b * (CIN * HW) + nb * 112;
  const uint4* asrc = weff + (size_t)(b * 4 + mb) * 16 * 512;

  // B-staging assignment: thread t owns unit ua=t (always) and ub=256+t (t<192).
  int ua = t, ka = ua / 112, ca = ua % 112;
  int ub = 256 + t, kb = ub / 112, cb = ub % 112;
  int pa = ua ^ ((ua >> 3) & 7);
  int pb = ub ^ ((ub >> 3) & 7);
  const float* xpa = xb + ka * 8 * HW + ca;
  const float* xpb = xb + kb * 8 * HW + cb;

  f32x4 acc[2][7] = {};

  for (int kk = 0; kk < 16; ++kk) {
    // --- load B slice to regs (global, fp32) ---
    const float* pA = xpa + kk * 32 * HW;
    const float* pB = xpb + kk * 32 * HW;
    float va[8], vb[8];
    #pragma unroll
    for (int ri = 0; ri < 8; ++ri) va[ri] = pA[ri * HW];
    if (t < 192) {
      #pragma unroll
      for (int ri = 0; ri < 8; ++ri) vb[ri] = pB[ri * HW];
    }

    __syncthreads();  // prev iteration's LDS reads done before overwrite

    // --- A: global_load_lds, 2 x 16B per thread (8KB slab) ---
    #pragma unroll
    for (int it = 0; it < 2; ++it)
      __builtin_amdgcn_global_load_lds((GU32*)(asrc + kk * 512 + it * 256 + t),
                                       (LU32*)(&ldsA[it * 256 + w * 64]), 16, 0, 0);

    // --- B: convert + pack 8 k-values -> one 16B unit, swizzled write ---
    {
      uint4 pk;
      pk.x = f2bf2(va[0], va[1]); pk.y = f2bf2(va[2], va[3]);
      pk.z = f2bf2(va[4], va[5]); pk.w = f2bf2(va[6], va[7]);
      ldsB[pa] = pk;
    }
    if (t < 192) {
      uint4 pk;
      pk.x = f2bf2(vb[0], vb[1]); pk.y = f2bf2(vb[2], vb[3]);
      pk.z = f2bf2(vb[4], vb[5]); pk.w = f2bf2(vb[6], vb[7]);
      ldsB[pb] = pk;
    }

    __syncthreads();  // drains vmcnt (glds) + lgkmcnt (ds_write)

    // --- fragments + MFMA ---
    bf16x8 af0 = *(const bf16x8*)&ldsA[l4 * 128 + w * 32 + l15];
    bf16x8 af1 = *(const bf16x8*)&ldsA[l4 * 128 + w * 32 + 16 + l15];
    #pragma unroll
    for (int u = 0; u < 7; ++u) {
      int un = l4 * 112 + u * 16 + l15;
      bf16x8 bf = *(const bf16x8*)&ldsB[un ^ ((un >> 3) & 7)];
      acc[0][u] = __builtin_amdgcn_mfma_f32_16x16x32_bf16(af0, bf, acc[0][u], 0, 0, 0);
      acc[1][u] = __builtin_amdgcn_mfma_f32_16x16x32_bf16(af1, bf, acc[1][u], 0, 0, 0);
    }
  }

  // --- epilogue: D layout col=lane&15, row=(lane>>4)*4+reg (m89-verified) ---
  int orow = mb * 128 + w * 32 + l4 * 4;
  int col = nb * 112 + l15;
  #pragma unroll
  for (int t16 = 0; t16 < 2; ++t16) {
    #pragma unroll
    for (int u = 0; u < 7; ++u) {
      float* op = out + ((size_t)b * COUT + orow + t16 * 16) * HW + col + u * 16;
      #pragma unroll
      for (int r = 0; r < 4; ++r) op[(size_t)r * HW] = acc[t16][u][r];
    }
  }
}

// ---------------- launcher -------------------------------------------------
extern "C" void kernel_launch(void* const* d_in, const int* in_sizes, int n_in,
                              void* d_out, int out_size, void* d_ws, size_t ws_size,
                              hipStream_t stream) {
  const float* x        = (const float*)d_in[0];
  const float* gate_w   = (const float*)d_in[1];
  const float* gate_b   = (const float*)d_in[2];
  const float* expert_w = (const float*)d_in[3];
  float* out = (float*)d_out;

  char* ws = (char*)d_ws;
  uint4* weff   = (uint4*)ws;                              // 33,554,432 B (bf16 tiled)
  float* pooled = (float*)(ws + 33554432);                 //    131,072 B
  float* g      = (float*)(ws + 33554432 + 131072);        //      2,048 B

  pool_kernel<<<8192, 256, 0, stream>>>(x, pooled);
  gate_kernel<<<1, 512, 0, stream>>>(pooled, gate_w, gate_b, g);
  weff_kernel<<<dim3(32, 4), 256, 0, stream>>>(expert_w, g, weff);
  gemm_kernel<<<dim3(7, 4, NB), 256, 0, stream>>>(weff, x, out);
}

// Round 3
// 127.418 us; speedup vs baseline: 1.4292x; 1.4292x over previous
//
#include <hip/hip_runtime.h>

// Problem constants: B=64, Cin=512, Cout=512, H=W=28 (HW=784), K=8 experts.
#define NB 64
#define CIN 512
#define COUT 512
#define HW 784
#define KEXP 8

typedef __attribute__((ext_vector_type(8))) short bf16x8;   // 8 bf16 = 4 VGPR (MFMA A/B frag)
typedef __attribute__((ext_vector_type(4))) float f32x4;    // MFMA C/D frag

typedef const __attribute__((address_space(1))) unsigned int GU32;
typedef __attribute__((address_space(3))) unsigned int LU32;

__device__ __forceinline__ unsigned f2bf1(float f) {
  unsigned u = __builtin_bit_cast(unsigned, f);
  return (u + 0x7FFFu + ((u >> 16) & 1u)) >> 16;   // RNE fp32->bf16
}
__device__ __forceinline__ unsigned f2bf2(float lo, float hi) {
  return f2bf1(lo) | (f2bf1(hi) << 16);
}

// ---------------- Kernel 1: pooled[b][c] = mean(x[b][c][:,:]) --------------
__global__ __launch_bounds__(256) void pool_kernel(const float* __restrict__ x,
                                                   float* __restrict__ pooled) {
  int w = threadIdx.x >> 6, lane = threadIdx.x & 63;
  int row = blockIdx.x * 4 + w;                     // < 32768 (grid 8192)
  const float4* xr = (const float4*)(x + (size_t)row * HW);
  float s = 0.f;
  for (int i = lane; i < 196; i += 64) {
    float4 v = xr[i];
    s += (v.x + v.y) + (v.z + v.w);
  }
  #pragma unroll
  for (int off = 32; off; off >>= 1) s += __shfl_down(s, off);
  if (lane == 0) pooled[row] = s * (1.0f / 784.0f);
}

// ---------------- Kernel 2: gate + sparsemax ------------------------------
__global__ __launch_bounds__(512) void gate_kernel(const float* __restrict__ pooled,
                                                   const float* __restrict__ gw,
                                                   const float* __restrict__ gb,
                                                   float* __restrict__ g) {
  __shared__ float lz[NB][KEXP];
  int t = threadIdx.x;
  int b = t >> 3, k = t & 7;
  const float4* pr = (const float4*)(pooled + b * CIN);
  const float4* wr = (const float4*)(gw + k * CIN);
  float s = 0.f;
  #pragma unroll 4
  for (int c4 = 0; c4 < 128; ++c4) {
    float4 p = pr[c4], q = wr[c4];
    s += p.x * q.x + p.y * q.y + p.z * q.z + p.w * q.w;
  }
  lz[b][k] = s + gb[k];
  __syncthreads();
  if (t < NB) {
    float z[8], zs[8];
    #pragma unroll
    for (int j = 0; j < 8; ++j) { z[j] = lz[t][j]; zs[j] = z[j]; }
    #pragma unroll
    for (int a = 1; a < 8; ++a) {
      float v = zs[a]; int j = a;
      while (j > 0 && zs[j - 1] < v) { zs[j] = zs[j - 1]; --j; }
      zs[j] = v;
    }
    float cums[8]; float csum = 0.f;
    #pragma unroll
    for (int j = 0; j < 8; ++j) { csum += zs[j]; cums[j] = csum; }
    int kz = 0;
    #pragma unroll
    for (int j = 0; j < 8; ++j)
      if (1.0f + (float)(j + 1) * zs[j] > cums[j]) kz = j + 1;
    float tau = (cums[kz - 1] - 1.0f) / (float)kz;
    #pragma unroll
    for (int j = 0; j < 8; ++j) g[t * 8 + j] = fmaxf(z[j] - tau, 0.0f);
  }
}

// ---------------- Kernel 3: w_eff builder (bf16, BM=256 GEMM-tiled) -------
// 16B-unit layout: unit(b,o,i) = b*32768 + ((o>>8)*16 + (i>>5))*1024
//                                + ((i>>3)&3)*256 + (o&255)
// -> per (b, mb, kk) a 16KB slab [kgrp(4)][row(256)][8 bf16], linear for
//    gemm's global_load_lds.
__global__ __launch_bounds__(256) void weff_kernel(const float* __restrict__ E,
                                                   const float* __restrict__ g,
                                                   uint4* __restrict__ wt) {
  __shared__ float gs[NB * KEXP];
  int t = threadIdx.x;
  ((float2*)gs)[t] = ((const float2*)g)[t];
  int o = blockIdx.x * 16 + (t & 15);
  int i = blockIdx.y * 128 + (t >> 4) * 8;
  float e[8][8];
  #pragma unroll
  for (int k = 0; k < 8; ++k) {
    const float4* p = (const float4*)(E + (size_t)k * (COUT * CIN) + (size_t)o * CIN + i);
    float4 a = p[0], c = p[1];
    e[k][0] = a.x; e[k][1] = a.y; e[k][2] = a.z; e[k][3] = a.w;
    e[k][4] = c.x; e[k][5] = c.y; e[k][6] = c.z; e[k][7] = c.w;
  }
  __syncthreads();
  int base = ((o >> 8) * 16 + (i >> 5)) * 1024 + ((i >> 3) & 3) * 256 + (o & 255);
  for (int b = 0; b < NB; ++b) {
    float acc[8] = {0, 0, 0, 0, 0, 0, 0, 0};
    #pragma unroll
    for (int k = 0; k < 8; ++k) {
      float gv = gs[b * 8 + k];
      #pragma unroll
      for (int j = 0; j < 8; ++j) acc[j] += gv * e[k][j];
    }
    uint4 pk;
    pk.x = f2bf2(acc[0], acc[1]); pk.y = f2bf2(acc[2], acc[3]);
    pk.z = f2bf2(acc[4], acc[5]); pk.w = f2bf2(acc[6], acc[7]);
    wt[(size_t)base + (size_t)b * 32768] = pk;
  }
}

// ---------------- Kernel 4: batched GEMM, BM=256 x BN=112, BK=32 ----------
// Grid 896 = 8 XCD x 8 batches x 14 (mb,nb). Bijective XCD swizzle puts all
// 14 blocks of one batch on ONE XCD (x[b] panel = 1.6MB < 4MiB L2) so x is
// fetched ~once from HBM.
__global__ __launch_bounds__(256) void gemm_kernel(const uint4* __restrict__ weff,
                                                   const float* __restrict__ x,
                                                   float* __restrict__ out) {
  __shared__ uint4 ldsA[1024];  // [kgrp4][row256] 16B units (16KB)
  __shared__ uint4 ldsB[448];   // [kgrp4][col112] 16B units, unit-XOR swizzled
  int id = blockIdx.x;
  int xcd = id & 7, s = id >> 3;          // round-robin XCD assumption
  int bloc = s / 14, inner = s - bloc * 14;
  int b = xcd * 8 + bloc;                 // 8 batches per XCD
  int mb = inner & 1, nb = inner >> 1;    // mb-pairs adjacent -> co-resident

  int t = threadIdx.x;
  int lane = t & 63, w = t >> 6;
  int l15 = lane & 15, l4 = lane >> 4;

  const float* xb = x + (size_t)b * (CIN * HW) + nb * 112;
  const uint4* asrc = weff + (size_t)b * 32768 + (size_t)mb * 16384;

  int ua = t, ka = ua / 112, ca = ua - ka * 112;
  int ub = 256 + t, kb = ub / 112, cb = ub - kb * 112;
  int pa = ua ^ ((ua >> 3) & 7);
  int pb = ub ^ ((ub >> 3) & 7);
  const float* xpa = xb + ka * 8 * HW + ca;
  const float* xpb = xb + kb * 8 * HW + cb;

  f32x4 acc[4][7] = {};

  for (int kk = 0; kk < 16; ++kk) {
    // B slice -> regs (fp32 global, strided rows / coalesced cols)
    const float* pA = xpa + kk * 32 * HW;
    const float* pB = xpb + kk * 32 * HW;
    float va[8], vb[8];
    #pragma unroll
    for (int ri = 0; ri < 8; ++ri) va[ri] = pA[ri * HW];
    if (t < 192) {
      #pragma unroll
      for (int ri = 0; ri < 8; ++ri) vb[ri] = pB[ri * HW];
    }

    __syncthreads();  // prev iteration's LDS reads done before overwrite

    // A: global_load_lds, 4 x 16B per thread (16KB slab)
    #pragma unroll
    for (int it = 0; it < 4; ++it)
      __builtin_amdgcn_global_load_lds((GU32*)(asrc + kk * 1024 + it * 256 + t),
                                       (LU32*)(&ldsA[it * 256 + w * 64]), 16, 0, 0);

    // B: convert + pack 8 k-values -> one 16B unit, swizzled write
    {
      uint4 pk;
      pk.x = f2bf2(va[0], va[1]); pk.y = f2bf2(va[2], va[3]);
      pk.z = f2bf2(va[4], va[5]); pk.w = f2bf2(va[6], va[7]);
      ldsB[pa] = pk;
    }
    if (t < 192) {
      uint4 pk;
      pk.x = f2bf2(vb[0], vb[1]); pk.y = f2bf2(vb[2], vb[3]);
      pk.z = f2bf2(vb[4], vb[5]); pk.w = f2bf2(vb[6], vb[7]);
      ldsB[pb] = pk;
    }

    __syncthreads();  // drains vmcnt (glds) + lgkmcnt (ds_write)

    // fragments + MFMA: wave w owns rows w*64..w*64+63
    bf16x8 af[4];
    #pragma unroll
    for (int m = 0; m < 4; ++m)
      af[m] = *(const bf16x8*)&ldsA[l4 * 256 + w * 64 + m * 16 + l15];
    #pragma unroll
    for (int u = 0; u < 7; ++u) {
      int un = l4 * 112 + u * 16 + l15;
      bf16x8 bf = *(const bf16x8*)&ldsB[un ^ ((un >> 3) & 7)];
      #pragma unroll
      for (int m = 0; m < 4; ++m)
        acc[m][u] = __builtin_amdgcn_mfma_f32_16x16x32_bf16(af[m], bf, acc[m][u], 0, 0, 0);
    }
  }

  // epilogue: D layout col=lane&15, row=(lane>>4)*4+reg (m89-verified)
  int orow0 = mb * 256 + w * 64 + l4 * 4;
  int col = nb * 112 + l15;
  #pragma unroll
  for (int m = 0; m < 4; ++m) {
    #pragma unroll
    for (int u = 0; u < 7; ++u) {
      float* op = out + ((size_t)b * COUT + orow0 + m * 16) * HW + col + u * 16;
      #pragma unroll
      for (int r = 0; r < 4; ++r) op[(size_t)r * HW] = acc[m][u][r];
    }
  }
}

// ---------------- launcher -------------------------------------------------
extern "C" void kernel_launch(void* const* d_in, const int* in_sizes, int n_in,
                              void* d_out, int out_size, void* d_ws, size_t ws_size,
                              hipStream_t stream) {
  const float* x        = (const float*)d_in[0];
  const float* gate_w   = (const float*)d_in[1];
  const float* gate_b   = (const float*)d_in[2];
  const float* expert_w = (const float*)d_in[3];
  float* out = (float*)d_out;

  char* ws = (char*)d_ws;
  uint4* weff   = (uint4*)ws;                              // 33,554,432 B (bf16 tiled)
  float* pooled = (float*)(ws + 33554432);                 //    131,072 B
  float* g      = (float*)(ws + 33554432 + 131072);        //      2,048 B

  pool_kernel<<<8192, 256, 0, stream>>>(x, pooled);
  gate_kernel<<<1, 512, 0, stream>>>(pooled, gate_w, gate_b, g);
  weff_kernel<<<dim3(32, 4), 256, 0, stream>>>(expert_w, g, weff);
  gemm_kernel<<<896, 256, 0, stream>>>(weff, x, out);
}